// Round 3
// baseline (177.135 us; speedup 1.0000x reference)
//
#include <hip/hip_runtime.h>
#include <hip/hip_bf16.h>

#define BETA_LOG2E 14.426950408889634f   // 10 * log2(e)
#define EPSN 1e-6f

typedef __bf16 bf16x8 __attribute__((ext_vector_type(8)));
typedef float  f32x4  __attribute__((ext_vector_type(4)));

static __device__ inline unsigned short f2bf(float f) {
    __hip_bfloat16 h = __float2bfloat16(f);
    return __builtin_bit_cast(unsigned short, h);
}
static __device__ inline float bf2f(unsigned short u) {
    unsigned int b = ((unsigned int)u) << 16;
    return __builtin_bit_cast(float, b);
}

// ---------------------------------------------------------------------------
// Kernel 1a: sum-of-squares partials, PURE STREAMING (contiguous 1KB segments
// per wave-instr). ssp[slab 8][which 2][b 4][n 4096]. Non-atomic slab split.
// grid 1024 = 2 tensor x 4 b x 8 cslab(32c) x 16 nspan(256n).
// ---------------------------------------------------------------------------
__global__ __launch_bounds__(256) void k_norm_ss(
    const float* __restrict__ f0, const float* __restrict__ f1,
    float* __restrict__ ssp)
{
    __shared__ f32x4 partial[4][64];

    int idx   = blockIdx.x;
    int which = idx >> 9;
    int rem   = idx & 511;
    int b     = rem >> 7;
    int cs    = (rem >> 4) & 7;
    int ns    = rem & 15;
    const float* src = which ? f1 : f0;

    int t  = threadIdx.x;
    int i  = t & 63;    // n4 index (wave-contiguous -> 1KB segments)
    int cr = t >> 6;    // 4 row groups
    int n0 = ns * 256;

    const float* sp = src + ((size_t)(b * 256 + cs * 32 + cr)) * 4096 + n0 + i * 4;

    f32x4 ss = {0.f, 0.f, 0.f, 0.f};
#pragma unroll
    for (int j = 0; j < 8; ++j) {
        f32x4 v = *reinterpret_cast<const f32x4*>(sp + (size_t)j * 4 * 4096);
        ss += v * v;
    }
    partial[cr][i] = ss;
    __syncthreads();
    if (t < 64) {
        f32x4 s4 = partial[0][t] + partial[1][t] + partial[2][t] + partial[3][t];
        size_t g = (size_t)cs * 32768 + which * 16384 + b * 4096 + n0 + t * 4;
        *reinterpret_cast<f32x4*>(&ssp[g]) = s4;
    }
}

// ---------------------------------------------------------------------------
// Kernel 1b: transpose + scale, reading f0/f1 L3-WARM (pass 1 touched all of
// it; 33MB << 256MB L3). Tile 64c x 256n staged as raw bf16 in LDS with XOR
// swizzle blk' = blk ^ ((c>>3)&7) -> conflict-free b128 writes AND u32 gather
// reads. Numerics = validated double-round (raw->bf16, scale, ->bf16).
// grid 512 = 2 tensor x 4 b x 16 ntile x 4 ctile.
// ---------------------------------------------------------------------------
__global__ __launch_bounds__(256) void k_transpose_scale(
    const float* __restrict__ f0, const float* __restrict__ f1,
    const float* __restrict__ ssp,
    unsigned short* __restrict__ aT, unsigned short* __restrict__ bT)
{
    __shared__ unsigned short tile[64 * 256];  // 32KB: [c][256 n], swizzled 16B blocks
    __shared__ float inv_l[256];

    int idx   = blockIdx.x;
    int which = idx >> 8;
    int rem   = idx & 255;
    int b     = rem >> 6;
    int nt    = (rem >> 2) & 15;
    int ct    = rem & 3;
    const float* src = which ? f1 : f0;
    unsigned short* dst = which ? bT : aT;

    int t  = threadIdx.x;
    int n0 = nt * 256;
    int c0 = ct * 64;

    // per-n inverse norms from the 8 slab partials
    {
        int gn = which * 16384 + b * 4096 + n0 + t;
        float s = 0.f;
#pragma unroll
        for (int sl = 0; sl < 8; ++sl) s += ssp[sl * 32768 + gn];
        inv_l[t] = 1.0f / fmaxf(sqrtf(s), EPSN);
    }

    // stage: thread (i32 = n8 idx, c8 = row octet); rows c = c8*8 + j.
    // 512B global segments per wave-instr; b128 LDS writes, blk' = i32 ^ c8.
    int i32 = t & 31;
    int c8  = t >> 5;
    const float* gp = src + ((size_t)(b * 256 + c0 + c8 * 8)) * 4096 + n0 + i32 * 8;
#pragma unroll
    for (int j = 0; j < 8; ++j) {
        f32x4 va = *reinterpret_cast<const f32x4*>(gp + (size_t)j * 4096);
        f32x4 vb = *reinterpret_cast<const f32x4*>(gp + (size_t)j * 4096 + 4);
        unsigned int pk[4];
        pk[0] = (unsigned int)f2bf(va[0]) | ((unsigned int)f2bf(va[1]) << 16);
        pk[1] = (unsigned int)f2bf(va[2]) | ((unsigned int)f2bf(va[3]) << 16);
        pk[2] = (unsigned int)f2bf(vb[0]) | ((unsigned int)f2bf(vb[1]) << 16);
        pk[3] = (unsigned int)f2bf(vb[2]) | ((unsigned int)f2bf(vb[3]) << 16);
        int c   = c8 * 8 + j;
        int blk = i32 ^ c8;                    // c8 == (c>>3)&7
        *reinterpret_cast<uint4*>(&tile[c * 256 + blk * 8]) =
            *reinterpret_cast<const uint4*>(pk);
    }
    __syncthreads();

    // gather-out: thread cg = t&7 owns c = cg*8..+7 (contiguous for the 16B
    // store); u32 reads pick an n-pair; banks spread by blk = (n>>3)^cg.
    int cg = t & 7;
#pragma unroll
    for (int iter = 0; iter < 4; ++iter) {
        int n   = iter * 64 + (t >> 3) * 2;    // even
        float ivA = inv_l[n], ivB = inv_l[n + 1];
        unsigned int oA[4], oB[4];
#pragma unroll
        for (int j = 0; j < 8; ++j) {
            int c   = cg * 8 + j;
            int blk = (n >> 3) ^ cg;           // cg == (c>>3)&7
            unsigned int u = *reinterpret_cast<const unsigned int*>(
                &tile[c * 256 + blk * 8 + (n & 7)]);
            unsigned short hA = f2bf(bf2f((unsigned short)(u & 0xffffu)) * ivA);
            unsigned short hB = f2bf(bf2f((unsigned short)(u >> 16)) * ivB);
            if (j & 1) { oA[j >> 1] |= ((unsigned int)hA) << 16;
                         oB[j >> 1] |= ((unsigned int)hB) << 16; }
            else       { oA[j >> 1]  = hA;  oB[j >> 1]  = hB; }
        }
        size_t base = ((size_t)(b * 4096 + n0 + n)) * 256 + c0 + cg * 8;
        *reinterpret_cast<uint4*>(&dst[base])       = *reinterpret_cast<const uint4*>(oA);
        *reinterpret_cast<uint4*>(&dst[base + 256]) = *reinterpret_cast<const uint4*>(oB);
    }
}

// ---------------------------------------------------------------------------
// Kernel 2 v4: flash cosine-sim + softmax stats.
// Round-0 geometry (512 blocks = 4 batch x 32 qt x 4 ks; FETCH ~12MB proven).
// NEW: LDS double-buffer (2 x 64keys x 512B = exactly 64KB, XOR ^(key&7) on
// 16B blocks instead of the 544B pad), ONE barrier per chunk, register
// prefetch with __launch_bounds__(256,2) so 32 VGPRs of vld DON'T spill
// (round-2 lesson: default bounds capped VGPR at 108 -> 110MB scratch writes).
// stats[q][ks] = {Z, Sx, Sy, Pmax}
// ---------------------------------------------------------------------------
__global__ __launch_bounds__(256, 2) void k_flash(
    const unsigned short* __restrict__ aT, const unsigned short* __restrict__ bT,
    float* __restrict__ stats)
{
    __shared__ unsigned short kbuf[2 * 64 * 256];  // 64KB double-buffered

    int idx   = blockIdx.x;
    int xcd   = idx & 7;                 // XCD swizzle: batch -> 2 XCDs
    int batch = xcd >> 1;
    int sub   = ((idx >> 3) << 1) | (xcd & 1);   // [0,128)
    int qt    = sub >> 2;                // [0,32)
    int ks    = sub & 3;                 // [0,4)

    int t    = threadIdx.x;
    int w    = t >> 6;
    int lane = t & 63;
    int quad = lane >> 4;
    int l15  = lane & 15;
    int q0w  = qt * 128 + w * 32;
    int k0   = ks * 1024;

    // resident A fragments: 2 strips of 16 queries x 8 K-steps
    bf16x8 afrag[2][8];
#pragma unroll
    for (int s = 0; s < 2; ++s) {
        const unsigned short* ap =
            aT + ((size_t)(batch * 4096 + q0w + s * 16 + l15)) * 256 + quad * 8;
#pragma unroll
        for (int kk = 0; kk < 8; ++kk)
            afrag[s][kk] = *reinterpret_cast<const bf16x8*>(ap + kk * 32);
    }

    // chunk-invariant swizzled read offsets: logical blk = quad + 4*kk,
    // stored at blk ^ (key&7) where key&7 == l15&7.
    int s7 = l15 & 7;
    int offs[8];
#pragma unroll
    for (int kk = 0; kk < 8; ++kk) offs[kk] = (((quad + 4 * kk) ^ s7) << 3);

    // staging write base: key = i*8 + (t>>5), blk = t&31 -> blk ^ (t>>5)
    int wbase = (t >> 5) * 256 + ((t & 31) ^ (t >> 5)) * 8;

    float Z[8], Sx[8], Sy[8], Sm[8];
#pragma unroll
    for (int i = 0; i < 8; ++i) { Z[i] = 0.f; Sx[i] = 0.f; Sy[i] = 0.f; Sm[i] = -1e30f; }

    const unsigned short* gbase = bT + ((size_t)(batch * 4096 + k0)) * 256;

    // prologue: stage chunk 0 into buf0
    uint4 vld[8];
#pragma unroll
    for (int i = 0; i < 8; ++i)
        vld[i] = *reinterpret_cast<const uint4*>(gbase + i * 2048 + t * 8);
#pragma unroll
    for (int i = 0; i < 8; ++i)
        *reinterpret_cast<uint4*>(&kbuf[i * 2048 + wbase]) = vld[i];
    __syncthreads();

    for (int ch = 0; ch < 16; ++ch) {
        int cur    = ch & 1;
        int bufOff = cur << 14;              // 16384 halfwords = 32KB

        // issue next chunk's global loads; latency hides under the MFMA loop
        if (ch < 15) {
            const unsigned short* g = gbase + (ch + 1) * 16384;
#pragma unroll
            for (int i = 0; i < 8; ++i)
                vld[i] = *reinterpret_cast<const uint4*>(g + i * 2048 + t * 8);
        }

        float Zc[8];
#pragma unroll
        for (int i = 0; i < 8; ++i) Zc[i] = 0.f;

#pragma unroll
        for (int nt = 0; nt < 4; ++nt) {
            f32x4 acc0 = {0.f, 0.f, 0.f, 0.f};
            f32x4 acc1 = {0.f, 0.f, 0.f, 0.f};
            const unsigned short* rb = &kbuf[bufOff + (nt * 16 + l15) * 256];
#pragma unroll
            for (int kk = 0; kk < 8; ++kk) {
                bf16x8 bfrag = *reinterpret_cast<const bf16x8*>(rb + offs[kk]);
                acc0 = __builtin_amdgcn_mfma_f32_16x16x32_bf16(afrag[0][kk], bfrag, acc0, 0, 0, 0);
                acc1 = __builtin_amdgcn_mfma_f32_16x16x32_bf16(afrag[1][kk], bfrag, acc1, 0, 0, 0);
            }
            float kx = (float)(nt * 16 + l15);     // key & 63
#pragma unroll
            for (int r = 0; r < 4; ++r) {
                float p0 = exp2f(acc0[r] * BETA_LOG2E);
                Zc[r]     += p0;  Sx[r]     += p0 * kx;
                Sm[r]      = fmaxf(Sm[r], acc0[r]);
                float p1 = exp2f(acc1[r] * BETA_LOG2E);
                Zc[4 + r] += p1;  Sx[4 + r] += p1 * kx;
                Sm[4 + r]  = fmaxf(Sm[4 + r], acc1[r]);
            }
        }
        float ky = (float)(ks * 16 + ch);          // (k0 + ch*64) >> 6
#pragma unroll
        for (int i = 0; i < 8; ++i) {
            Z[i]  += Zc[i];
            Sy[i]  = fmaf(ky, Zc[i], Sy[i]);
        }

        // write prefetched chunk into the other buffer (its readers finished
        // before the PREVIOUS barrier), then one barrier ends the chunk
        if (ch < 15) {
            int nb = (cur ^ 1) << 14;
#pragma unroll
            for (int i = 0; i < 8; ++i)
                *reinterpret_cast<uint4*>(&kbuf[nb + i * 2048 + wbase]) = vld[i];
        }
        __syncthreads();
    }

    // reduce across the 16 col-lanes (low 4 lane bits)
#pragma unroll
    for (int i = 0; i < 8; ++i) {
#pragma unroll
        for (int m = 1; m <= 8; m <<= 1) {
            Z[i]  += __shfl_xor(Z[i], m);
            Sx[i] += __shfl_xor(Sx[i], m);
            Sy[i] += __shfl_xor(Sy[i], m);
            Sm[i]  = fmaxf(Sm[i], __shfl_xor(Sm[i], m));
        }
    }
    if (l15 == 0) {
#pragma unroll
        for (int s = 0; s < 2; ++s)
#pragma unroll
            for (int r = 0; r < 4; ++r) {
                int q = q0w + s * 16 + quad * 4 + r;   // C/D row = quad*4+reg
                f32x4 st = {Z[s * 4 + r], Sx[s * 4 + r], Sy[s * 4 + r],
                            exp2f(Sm[s * 4 + r] * BETA_LOG2E)};
                *reinterpret_cast<f32x4*>(&stats[((size_t)(batch * 4096 + q) * 4 + ks) * 4]) = st;
            }
    }
}

// ---------------------------------------------------------------------------
// Kernel 3: merge 4 key-splits, write warp (x,y interleaved) then cert.
// ---------------------------------------------------------------------------
__global__ __launch_bounds__(256) void k_finalize(
    const float* __restrict__ stats, float* __restrict__ out)
{
    int q = blockIdx.x * 256 + threadIdx.x;   // [0, 16384)
    const f32x4* s = reinterpret_cast<const f32x4*>(stats + (size_t)q * 16);
    f32x4 a0 = s[0], a1 = s[1], a2 = s[2], a3 = s[3];
    float Z  = a0.x + a1.x + a2.x + a3.x;
    float Sx = a0.y + a1.y + a2.y + a3.y;
    float Sy = a0.z + a1.z + a2.z + a3.z;
    float Pm = fmaxf(fmaxf(a0.w, a1.w), fmaxf(a2.w, a3.w));
    float invZ = 1.0f / Z;
    out[q * 2 + 0]  = Sx * invZ;
    out[q * 2 + 1]  = Sy * invZ;
    out[32768 + q]  = Pm * invZ;
}

extern "C" void kernel_launch(void* const* d_in, const int* in_sizes, int n_in,
                              void* d_out, int out_size, void* d_ws, size_t ws_size,
                              hipStream_t stream)
{
    const float* f0 = (const float*)d_in[0];
    const float* f1 = (const float*)d_in[1];
    unsigned short* aT = (unsigned short*)d_ws;           // 8 MB
    unsigned short* bT = aT + (size_t)4 * 4096 * 256;     // 8 MB
    float* stats = (float*)(bT + (size_t)4 * 4096 * 256); // 1 MB
    float* ssp   = stats + (size_t)16384 * 16;            // 1 MB (8 slabs x 32768)
    float* out = (float*)d_out;

    hipLaunchKernelGGL(k_norm_ss,          dim3(1024), dim3(256), 0, stream, f0, f1, ssp);
    hipLaunchKernelGGL(k_transpose_scale,  dim3(512),  dim3(256), 0, stream, f0, f1, ssp, aT, bT);
    hipLaunchKernelGGL(k_flash,            dim3(512),  dim3(256), 0, stream, aT, bT, stats);
    hipLaunchKernelGGL(k_finalize,         dim3(64),   dim3(256), 0, stream, stats, out);
}

// Round 5
// 134.382 us; speedup vs baseline: 1.3182x; 1.3182x over previous
//
#include <hip/hip_runtime.h>
#include <hip/hip_bf16.h>

#define BETA_LOG2E 14.426950408889634f   // 10 * log2(e)
#define EPSN 1e-6f

typedef __bf16 bf16x8 __attribute__((ext_vector_type(8)));
typedef float  f32x4  __attribute__((ext_vector_type(4)));

static __device__ inline unsigned short f2bf(float f) {
    __hip_bfloat16 h = __float2bfloat16(f);
    return __builtin_bit_cast(unsigned short, h);
}
static __device__ inline float bf2f(unsigned short u) {
    unsigned int b = ((unsigned int)u) << 16;
    return __builtin_bit_cast(float, b);
}

// ---------------------------------------------------------------------------
// Kernel 1 (best measured variant, round-2 v3): L2-normalize over C, transpose
// [b][c][n] -> [b][n][c], bf16. 1024 blocks (4/CU), tile 32n x 256c,
// 8 x f32x4 loads/thread. Numerics: raw->bf16, scale, ->bf16 (validated).
// ---------------------------------------------------------------------------
__global__ __launch_bounds__(256) void k_norm_transpose(
    const float* __restrict__ f0, const float* __restrict__ f1,
    unsigned short* __restrict__ aT, unsigned short* __restrict__ bT)
{
    __shared__ unsigned short tile[32 * 256];  // [n][c] raw bf16
    __shared__ float partial[32][32];          // [cg][n]
    __shared__ float inv_l[32];

    int idx   = blockIdx.x;
    int which = idx >> 9;
    int rem   = idx & 511;
    int b     = rem >> 7;
    int n0    = (rem & 127) * 32;
    const float* src = which ? f1 : f0;
    unsigned short* dst = which ? bT : aT;

    int t  = threadIdx.x;
    int nq = t & 7;     // 8 quads of 4 n  -> 32 n
    int cg = t >> 3;    // 32 groups of 8 c -> 256 c

    const float* sp = src + ((size_t)(b * 256 + cg * 8)) * 4096 + n0 + nq * 4;

    f32x4 ss = {0.f, 0.f, 0.f, 0.f};
    unsigned int pk[4][4];   // [j = n sub-row][4 uints = 8 bf16 over c]
#pragma unroll
    for (int i = 0; i < 8; ++i) {
        f32x4 v = *reinterpret_cast<const f32x4*>(sp + (size_t)i * 4096);
        ss += v * v;
#pragma unroll
        for (int j = 0; j < 4; ++j) {
            unsigned int h = f2bf(v[j]);
            if (i & 1) pk[j][i >> 1] |= h << 16;
            else       pk[j][i >> 1]  = h;
        }
    }
#pragma unroll
    for (int j = 0; j < 4; ++j) {
        int n = nq * 4 + j;
        *reinterpret_cast<uint4*>(&tile[n * 256 + cg * 8]) =
            *reinterpret_cast<const uint4*>(pk[j]);
    }
    *reinterpret_cast<f32x4*>(&partial[cg][nq * 4]) = ss;
    __syncthreads();
    if (t < 32) {
        float s = 0.f;
#pragma unroll
        for (int k = 0; k < 32; ++k) s += partial[k][t];
        inv_l[t] = 1.0f / fmaxf(sqrtf(s), EPSN);
    }
    __syncthreads();

#pragma unroll
    for (int it = 0; it < 4; ++it) {
        int n  = it * 8 + (t >> 5);
        int cb = t & 31;
        uint4 v = *reinterpret_cast<const uint4*>(&tile[n * 256 + cb * 8]);
        float inv = inv_l[n];
        unsigned int o[4];
#pragma unroll
        for (int k = 0; k < 4; ++k) {
            unsigned int u = (&v.x)[k];
            unsigned short lo = f2bf(bf2f((unsigned short)(u & 0xffffu)) * inv);
            unsigned short hi = f2bf(bf2f((unsigned short)(u >> 16)) * inv);
            o[k] = (unsigned int)lo | ((unsigned int)hi << 16);
        }
        *reinterpret_cast<uint4*>(&dst[((size_t)(b * 4096 + n0 + n)) * 256 + cb * 8]) =
            *reinterpret_cast<const uint4*>(o);
    }
}

// ---------------------------------------------------------------------------
// Kernel 2 v6: BYTE-EXACT round-0 body (VGPR 92, 0 bank conflicts, WRITE 2MB
// proven; no prefetch, no Zc hoist -- rounds 1-3 showed any register-pressure
// change flips the regalloc tier and spills) with exactly two deltas:
//   (a) keysplit 4 -> 8, grid 1024 = 4 blocks/CU (16 waves/CU): staging and
//       barrier stalls of one block overlap compute of the other three.
//       Per-XCD working set is ks-independent (aT 2MB + bT 2MB = 4MB = L2).
//   (b) T5 s_setprio(1) around the MFMA cluster (zero register impact).
// stats[q][ks] = {Z, Sx, Sy, Pmax}
// ---------------------------------------------------------------------------
__global__ __launch_bounds__(256) void k_flash(
    const unsigned short* __restrict__ aT, const unsigned short* __restrict__ bT,
    float* __restrict__ stats)
{
    __shared__ unsigned short kbuf[64 * 272];  // 64 keys x 272 halfwords (544 B)

    int idx   = blockIdx.x;
    int xcd   = idx & 7;                 // XCD swizzle: batch -> 2 XCDs (L2 locality)
    int batch = xcd >> 1;
    int sub   = ((idx >> 3) << 1) | (xcd & 1);   // [0,256)
    int qt    = sub >> 3;                // [0,32)
    int ks    = sub & 7;                 // [0,8)

    int t    = threadIdx.x;
    int w    = t >> 6;
    int lane = t & 63;
    int quad = lane >> 4;
    int l15  = lane & 15;
    int q0w  = qt * 128 + w * 32;
    int k0   = ks * 512;

    // resident A fragments: 2 strips of 16 queries x 8 K-steps
    bf16x8 afrag[2][8];
#pragma unroll
    for (int s = 0; s < 2; ++s) {
        const unsigned short* ap =
            aT + ((size_t)(batch * 4096 + q0w + s * 16 + l15)) * 256 + quad * 8;
#pragma unroll
        for (int kk = 0; kk < 8; ++kk)
            afrag[s][kk] = *reinterpret_cast<const bf16x8*>(ap + kk * 32);
    }

    float Z[8], Sx[8], Sy[8], Pm[8];
#pragma unroll
    for (int i = 0; i < 8; ++i) { Z[i] = 0.f; Sx[i] = 0.f; Sy[i] = 0.f; Pm[i] = 0.f; }

    for (int ch = 0; ch < 8; ++ch) {
        int kbase = k0 + ch * 64;
        const unsigned short* gsrc = bT + ((size_t)(batch * 4096 + kbase)) * 256;
        // stage 64 keys x 512B -> LDS with 544B row stride (bank-balanced)
#pragma unroll
        for (int i = 0; i < 8; ++i) {
            int h = i * 2048 + t * 8;                      // halfword idx in chunk
            uint4 v = *reinterpret_cast<const uint4*>(gsrc + h);
            int key  = i * 8 + (t >> 5);
            int gran = t & 31;
            *reinterpret_cast<uint4*>(&kbuf[key * 272 + gran * 8]) = v;
        }
        __syncthreads();

#pragma unroll
        for (int nt = 0; nt < 4; ++nt) {
            f32x4 acc0 = {0.f, 0.f, 0.f, 0.f};
            f32x4 acc1 = {0.f, 0.f, 0.f, 0.f};
            const unsigned short* lp = &kbuf[(nt * 16 + l15) * 272 + quad * 8];
            __builtin_amdgcn_s_setprio(1);
#pragma unroll
            for (int kk = 0; kk < 8; ++kk) {
                bf16x8 bfrag = *reinterpret_cast<const bf16x8*>(lp + kk * 32);
                acc0 = __builtin_amdgcn_mfma_f32_16x16x32_bf16(afrag[0][kk], bfrag, acc0, 0, 0, 0);
                acc1 = __builtin_amdgcn_mfma_f32_16x16x32_bf16(afrag[1][kk], bfrag, acc1, 0, 0, 0);
            }
            __builtin_amdgcn_s_setprio(0);
            int key  = kbase + nt * 16 + l15;   // C/D col = lane&15 = key
            float kx = (float)(key & 63);
            float ky = (float)(key >> 6);
#pragma unroll
            for (int r = 0; r < 4; ++r) {
                float p0 = exp2f(acc0[r] * BETA_LOG2E);
                Z[r]  += p0;  Sx[r] += p0 * kx;  Sy[r] += p0 * ky;
                Pm[r] = fmaxf(Pm[r], p0);
                float p1 = exp2f(acc1[r] * BETA_LOG2E);
                Z[4 + r]  += p1;  Sx[4 + r] += p1 * kx;  Sy[4 + r] += p1 * ky;
                Pm[4 + r] = fmaxf(Pm[4 + r], p1);
            }
        }
        __syncthreads();
    }

    // reduce across the 16 col-lanes (low 4 lane bits)
#pragma unroll
    for (int i = 0; i < 8; ++i) {
#pragma unroll
        for (int m = 1; m <= 8; m <<= 1) {
            Z[i]  += __shfl_xor(Z[i], m);
            Sx[i] += __shfl_xor(Sx[i], m);
            Sy[i] += __shfl_xor(Sy[i], m);
            Pm[i]  = fmaxf(Pm[i], __shfl_xor(Pm[i], m));
        }
    }
    if (l15 == 0) {
#pragma unroll
        for (int s = 0; s < 2; ++s)
#pragma unroll
            for (int r = 0; r < 4; ++r) {
                int q = q0w + s * 16 + quad * 4 + r;   // C/D row = quad*4+reg
                f32x4 st = {Z[s * 4 + r], Sx[s * 4 + r], Sy[s * 4 + r], Pm[s * 4 + r]};
                *reinterpret_cast<f32x4*>(&stats[((size_t)(batch * 4096 + q) * 8 + ks) * 4]) = st;
            }
    }
}

// ---------------------------------------------------------------------------
// Kernel 3: merge 8 key-splits, write warp (x,y interleaved) then cert.
// ---------------------------------------------------------------------------
__global__ __launch_bounds__(256) void k_finalize(
    const float* __restrict__ stats, float* __restrict__ out)
{
    int q = blockIdx.x * 256 + threadIdx.x;   // [0, 16384)
    const f32x4* s = reinterpret_cast<const f32x4*>(stats + (size_t)q * 32);
    float Z = 0.f, Sx = 0.f, Sy = 0.f, Pm = 0.f;
#pragma unroll
    for (int k = 0; k < 8; ++k) {
        f32x4 a = s[k];
        Z += a.x; Sx += a.y; Sy += a.z; Pm = fmaxf(Pm, a.w);
    }
    float invZ = 1.0f / Z;
    out[q * 2 + 0]  = Sx * invZ;
    out[q * 2 + 1]  = Sy * invZ;
    out[32768 + q]  = Pm * invZ;
}

extern "C" void kernel_launch(void* const* d_in, const int* in_sizes, int n_in,
                              void* d_out, int out_size, void* d_ws, size_t ws_size,
                              hipStream_t stream)
{
    const float* f0 = (const float*)d_in[0];
    const float* f1 = (const float*)d_in[1];
    unsigned short* aT = (unsigned short*)d_ws;           // 8 MB
    unsigned short* bT = aT + (size_t)4 * 4096 * 256;     // 8 MB
    float* stats = (float*)(bT + (size_t)4 * 4096 * 256); // 16384*8*4 f32 = 2 MB
    float* out = (float*)d_out;

    hipLaunchKernelGGL(k_norm_transpose, dim3(1024), dim3(256), 0, stream, f0, f1, aT, bT);
    hipLaunchKernelGGL(k_flash,          dim3(1024), dim3(256), 0, stream, aT, bT, stats);
    hipLaunchKernelGGL(k_finalize,       dim3(64),   dim3(256), 0, stream, stats, out);
}